// Round 2
// baseline (628.413 us; speedup 1.0000x reference)
//
#include <hip/hip_runtime.h>
#include <hip/hip_fp16.h>

#define DEVI __device__ __forceinline__

typedef _Float16 f16x8 __attribute__((ext_vector_type(8)));
typedef float f32x4 __attribute__((ext_vector_type(4)));

static DEVI unsigned short f2h_u(float f) {
    _Float16 h = (_Float16)f;
    return __builtin_bit_cast(unsigned short, h);
}
static DEVI float h2f_u(unsigned short u) {
    return (float)__builtin_bit_cast(_Float16, u);
}
static DEVI unsigned pk2(float a, float b) {
    return (unsigned)f2h_u(a) | ((unsigned)f2h_u(b) << 16);
}

// problem constants
// B=32 Q=300 D=256 H=8 C=32 S=8400 levels (80,80)(40,40)(20,20) P=12

// ---------------- kernel 0: weight transpose/convert + combined bias ----------------
__global__ __launch_bounds__(256) void prep_weights(
    const float* __restrict__ W_val, const float* __restrict__ W_off,
    const float* __restrict__ W_attn, const float* __restrict__ W_out,
    const float* __restrict__ b_off, const float* __restrict__ b_attn,
    unsigned short* __restrict__ Wvt, unsigned short* __restrict__ Wct,
    unsigned short* __restrict__ Wot, float* __restrict__ cbias)
{
    int idx = blockIdx.x * 256 + threadIdx.x;
    if (idx < 65536) {
        int n = idx >> 8, k = idx & 255;
        Wvt[idx] = f2h_u(W_val[k * 256 + n]);
    } else if (idx < 65536 + 73728) {
        int j = idx - 65536;
        int n = j >> 8, k = j & 255;
        Wct[j] = f2h_u(n < 192 ? W_off[k * 192 + n] : W_attn[k * 96 + (n - 192)]);
    } else if (idx < 204800) {
        int j = idx - 139264;
        int n = j >> 8, k = j & 255;
        Wot[j] = f2h_u(W_out[k * 256 + n]);
    } else if (idx < 205088) {
        int j = idx - 204800;
        cbias[j] = (j < 192) ? b_off[j] : b_attn[j - 192];
    }
}

// ---------------- templated MFMA GEMM: C = A(f32, Mx256) * Wt^T + bias ----------------
// Wt pre-transposed f16 [N][256]. BM=64, BK=32, K=256 (8 iters).
// Register double-buffer of the staging loads (A and B prefetched for kt+1
// before the MFMA section of kt) so global latency overlaps compute.
// OUT_F16 epilogue stages C as f16 in LDS -> LDS ~17.4KB -> ~2x occupancy.
template<int BN, bool OUT_F16>
__global__ __launch_bounds__(256) void gemm_f16(
    const float* __restrict__ A, const unsigned short* __restrict__ Wt,
    const float* __restrict__ bias, void* __restrict__ outp, int ldo)
{
    constexpr int NI  = BN / 16;
    constexpr int NB  = (BN * 4 + 255) / 256;   // B stage chunks per thread
    constexpr bool BEXACT = (BN * 4 % 256) == 0;
    constexpr int LDA = 40;        // ushorts per As row
    constexpr int LDB = 40;
    constexpr int LDC = BN + 4;    // f32 epilogue leading dim (floats)
    constexpr int LDH = BN + 8;    // f16 epilogue leading dim (ushorts)
    constexpr int SM1 = 64 * LDA * 2 + BN * LDB * 2;
    constexpr int SM2 = OUT_F16 ? (64 * LDH * 2) : (64 * LDC * 4);
    constexpr int SMEM = SM1 > SM2 ? SM1 : SM2;
    __shared__ __align__(16) char smem[SMEM];
    unsigned short* As = (unsigned short*)smem;
    unsigned short* Bs = (unsigned short*)(smem + 64 * LDA * 2);

    const int tid  = threadIdx.x;
    const int wave = tid >> 6;
    const int lane = tid & 63;
    const int l15  = lane & 15;
    const int qd   = lane >> 4;
    const int m0   = blockIdx.y * 64;
    const int n0   = blockIdx.x * BN;

    // A staging: thread owns (row=tid>>3, col4=tid&7) and (+32 rows)
    const int ar0 = tid >> 3;
    const int ac0 = (tid & 7) * 4;
    const float* aptr0 = A + (size_t)(m0 + ar0) * 256 + ac0;
    const float* aptr1 = aptr0 + 32 * 256;

    f32x4 acc[NI];
#pragma unroll
    for (int i = 0; i < NI; i++) acc[i] = (f32x4){0.f, 0.f, 0.f, 0.f};

    // prefetch kt=0
    float4 apf0 = *(const float4*)(aptr0);
    float4 apf1 = *(const float4*)(aptr1);
    uint4 bpf[NB];
#pragma unroll
    for (int j = 0; j < NB; j++) {
        int f = tid + j * 256;
        if (BEXACT || f < BN * 4) {
            int row = f >> 2, ch = f & 3;
            bpf[j] = *(const uint4*)(Wt + (size_t)(n0 + row) * 256 + ch * 8);
        }
    }

#pragma unroll
    for (int kt = 0; kt < 8; kt++) {
        if (kt) __syncthreads();                 // LDS free (prev MFMA done)
        // store staged regs -> LDS
        {
            uint2 p0; p0.x = pk2(apf0.x, apf0.y); p0.y = pk2(apf0.z, apf0.w);
            *(uint2*)&As[ar0 * LDA + ac0] = p0;
            uint2 p1; p1.x = pk2(apf1.x, apf1.y); p1.y = pk2(apf1.z, apf1.w);
            *(uint2*)&As[(ar0 + 32) * LDA + ac0] = p1;
        }
#pragma unroll
        for (int j = 0; j < NB; j++) {
            int f = tid + j * 256;
            if (BEXACT || f < BN * 4) {
                int row = f >> 2, ch = f & 3;
                *(uint4*)&Bs[row * LDB + ch * 8] = bpf[j];
            }
        }
        __syncthreads();
        // prefetch kt+1 (overlaps ds_read + MFMA below)
        if (kt < 7) {
            apf0 = *(const float4*)(aptr0 + (kt + 1) * 32);
            apf1 = *(const float4*)(aptr1 + (kt + 1) * 32);
#pragma unroll
            for (int j = 0; j < NB; j++) {
                int f = tid + j * 256;
                if (BEXACT || f < BN * 4) {
                    int row = f >> 2, ch = f & 3;
                    bpf[j] = *(const uint4*)(Wt + (size_t)(n0 + row) * 256 + (kt + 1) * 32 + ch * 8);
                }
            }
        }
        f16x8 af = *(const f16x8*)&As[(wave * 16 + l15) * LDA + qd * 8];
#pragma unroll
        for (int ni = 0; ni < NI; ni++) {
            f16x8 fb = *(const f16x8*)&Bs[(ni * 16 + l15) * LDB + qd * 8];
            acc[ni] = __builtin_amdgcn_mfma_f32_16x16x32_f16(af, fb, acc[ni], 0, 0, 0);
        }
    }
    __syncthreads();   // MFMA ds_reads done before LDS reuse by epilogue

    if (OUT_F16) {
        unsigned short* Ch = (unsigned short*)smem;
#pragma unroll
        for (int ni = 0; ni < NI; ni++) {
            const float bb = bias[n0 + ni * 16 + l15];
#pragma unroll
            for (int r = 0; r < 4; r++) {
                Ch[(wave * 16 + qd * 4 + r) * LDH + ni * 16 + l15] = f2h_u(acc[ni][r] + bb);
            }
        }
        __syncthreads();
        for (int f = tid; f < 64 * (BN / 8); f += 256) {
            int row = f / (BN / 8), c8 = f % (BN / 8);
            uint4 v = *(uint4*)&Ch[row * LDH + c8 * 8];
            *(uint4*)((unsigned short*)outp + (size_t)(m0 + row) * ldo + n0 + c8 * 8) = v;
        }
    } else {
        float* Cs = (float*)smem;
#pragma unroll
        for (int ni = 0; ni < NI; ni++) {
#pragma unroll
            for (int r = 0; r < 4; r++) {
                Cs[(wave * 16 + qd * 4 + r) * LDC + ni * 16 + l15] = acc[ni][r];
            }
        }
        __syncthreads();
        for (int f = tid; f < 64 * (BN / 4); f += 256) {
            int row = f / (BN / 4), c4 = f % (BN / 4);
            float4 v = *(const float4*)&Cs[row * LDC + c4 * 4];
            const float4 bb = *(const float4*)(bias + n0 + c4 * 4);
            v.x += bb.x; v.y += bb.y; v.z += bb.z; v.w += bb.w;
            *(float4*)((float*)outp + (size_t)(m0 + row) * ldo + n0 + c4 * 4) = v;
        }
    }
}

// ---------------- fused softmax + location + bilinear sampling + attn weighting ----------------
__global__ __launch_bounds__(256) void sample_attn(
    const float* __restrict__ P, const float* __restrict__ refp,
    const unsigned short* __restrict__ val, float* __restrict__ out_attn)
{
    __shared__ float sLog[8][12];
    __shared__ float sLoc[8][12][3];
    const int row = blockIdx.x;          // b*300 + q
    const int b = row / 300;
    const int tid = threadIdx.x;

    const float4 r4 = *(const float4*)(refp + (size_t)row * 4);

    int h = 0, p = 0;
    float offx = 0.f, offy = 0.f, logit = 0.f;
    if (tid < 96) {
        h = tid / 12;
        p = tid - h * 12;
        const float* Pr = P + (size_t)row * 288;
        offx  = Pr[h * 24 + p * 2];
        offy  = Pr[h * 24 + p * 2 + 1];
        logit = Pr[192 + h * 12 + p];
        sLog[h][p] = logit;
    }
    __syncthreads();
    if (tid < 96) {
        float m = -1e30f;
#pragma unroll
        for (int j = 0; j < 12; j++) m = fmaxf(m, sLog[h][j]);
        float s = 0.f;
#pragma unroll
        for (int j = 0; j < 12; j++) s += expf(sLog[h][j] - m);
        float w = expf(logit - m) / s;
        sLoc[h][p][0] = r4.x + offx * 0.125f * r4.z;
        sLoc[h][p][1] = r4.y + offy * 0.125f * r4.w;
        sLoc[h][p][2] = w;
    }
    __syncthreads();

    const int hh = tid >> 5, c = tid & 31;
    const unsigned short* vb = val + (size_t)b * 8400 * 256 + hh * 32 + c;
    float acc = 0.f;
#pragma unroll
    for (int p2 = 0; p2 < 12; p2++) {
        const int lvl  = p2 >> 2;
        const int W    = (lvl == 0) ? 80 : ((lvl == 1) ? 40 : 20);
        const int Hh   = W;
        const int loff = (lvl == 0) ? 0 : ((lvl == 1) ? 6400 : 8000);
        const float lx = sLoc[hh][p2][0];
        const float ly = sLoc[hh][p2][1];
        const float w  = sLoc[hh][p2][2];
        const float px = lx * (float)W - 0.5f;
        const float py = ly * (float)Hh - 0.5f;
        const float x0f = floorf(px), y0f = floorf(py);
        const float fx = px - x0f, fy = py - y0f;
        const int x0 = (int)x0f, y0 = (int)y0f;
        const int x1 = x0 + 1, y1 = y0 + 1;
        const float w00 = (1.f - fx) * (1.f - fy);
        const float w10 = fx * (1.f - fy);
        const float w01 = (1.f - fx) * fy;
        const float w11 = fx * fy;
        const bool vx0 = (x0 >= 0) && (x0 < W);
        const bool vx1 = (x1 >= 0) && (x1 < W);
        const bool vy0 = (y0 >= 0) && (y0 < Hh);
        const bool vy1 = (y1 >= 0) && (y1 < Hh);
        const int x0c = min(max(x0, 0), W - 1), x1c = min(max(x1, 0), W - 1);
        const int y0c = min(max(y0, 0), Hh - 1), y1c = min(max(y1, 0), Hh - 1);
        const float v00 = h2f_u(vb[(size_t)(loff + y0c * W + x0c) * 256]);
        const float v10 = h2f_u(vb[(size_t)(loff + y0c * W + x1c) * 256]);
        const float v01 = h2f_u(vb[(size_t)(loff + y1c * W + x0c) * 256]);
        const float v11 = h2f_u(vb[(size_t)(loff + y1c * W + x1c) * 256]);
        float sv = 0.f;
        sv += (vx0 && vy0) ? w00 * v00 : 0.f;
        sv += (vx1 && vy0) ? w10 * v10 : 0.f;
        sv += (vx0 && vy1) ? w01 * v01 : 0.f;
        sv += (vx1 && vy1) ? w11 * v11 : 0.f;
        acc += w * sv;
    }
    out_attn[(size_t)row * 256 + tid] = acc;
}

extern "C" void kernel_launch(void* const* d_in, const int* in_sizes, int n_in,
                              void* d_out, int out_size, void* d_ws, size_t ws_size,
                              hipStream_t stream)
{
    const float* hs     = (const float*)d_in[0];
    const float* enc    = (const float*)d_in[1];
    const float* refp   = (const float*)d_in[2];
    const float* W_off  = (const float*)d_in[3];
    const float* b_off  = (const float*)d_in[4];
    const float* W_attn = (const float*)d_in[5];
    const float* b_attn = (const float*)d_in[6];
    const float* W_val  = (const float*)d_in[7];
    const float* b_val  = (const float*)d_in[8];
    const float* W_out  = (const float*)d_in[9];
    const float* b_out  = (const float*)d_in[10];
    float* outp = (float*)d_out;

    // workspace layout (bytes)
    char* ws = (char*)d_ws;
    unsigned short* val = (unsigned short*)ws;                 // 268800*256*2 = 137,625,600
    float* P            = (float*)(ws + 137625600);            // 9600*288*4   =  11,059,200
    float* oattn        = (float*)(ws + 148684800);            // 9600*256*4   =   9,830,400
    unsigned short* Wvt = (unsigned short*)(ws + 158515200);   // 256*256*2
    unsigned short* Wct = (unsigned short*)(ws + 158646272);   // 288*256*2
    unsigned short* Wot = (unsigned short*)(ws + 158793728);   // 256*256*2
    float* cbias        = (float*)(ws + 158924800);            // 288*4

    prep_weights<<<802, 256, 0, stream>>>(W_val, W_off, W_attn, W_out,
                                          b_off, b_attn, Wvt, Wct, Wot, cbias);
    // proj: (9600x256) @ (256x288) -> P (f32)
    gemm_f16<96, false><<<dim3(3, 150), 256, 0, stream>>>(hs, Wct, cbias, P, 288);
    // value: (268800x256) @ (256x256) -> val (f16)
    gemm_f16<128, true ><<<dim3(2, 4200), 256, 0, stream>>>(enc, Wvt, b_val, val, 256);
    // fused sampling
    sample_attn<<<9600, 256, 0, stream>>>(P, refp, val, oattn);
    // out: (9600x256) @ (256x256) -> d_out (f32)
    gemm_f16<64, false><<<dim3(4, 150), 256, 0, stream>>>(oattn, Wot, b_out, outp, 256);
}

// Round 3
// 477.449 us; speedup vs baseline: 1.3162x; 1.3162x over previous
//
#include <hip/hip_runtime.h>
#include <hip/hip_fp16.h>

#define DEVI __device__ __forceinline__

typedef _Float16 f16x8 __attribute__((ext_vector_type(8)));
typedef float f32x4 __attribute__((ext_vector_type(4)));

static DEVI unsigned short f2h_u(float f) {
    _Float16 h = (_Float16)f;
    return __builtin_bit_cast(unsigned short, h);
}
static DEVI float h2f_u(unsigned short u) {
    return (float)__builtin_bit_cast(_Float16, u);
}
static DEVI unsigned pk2(float a, float b) {
    return (unsigned)f2h_u(a) | ((unsigned)f2h_u(b) << 16);
}

// problem constants
// B=32 Q=300 D=256 H=8 C=32 S=8400 levels (80,80)(40,40)(20,20) P=12

// ---------------- kernel 0: weight prep ----------------
// Wst: W_val staged in value-GEMM LDS order: [half(2)][kgrp(32)][n(128)][8]
//      element (n,k):  Wst[((n>>7)*32 + (k>>3))*1024 + (n&127)*8 + (k&7)]
// Wct[n][k] = f16(n<192 ? W_off[k][n] : W_attn[k][n-192])  (288x256, n-major)
// Wot[n][k] = f16(W_out[k][n])  (256x256, n-major)
__global__ __launch_bounds__(256) void prep_weights(
    const float* __restrict__ W_val, const float* __restrict__ W_off,
    const float* __restrict__ W_attn, const float* __restrict__ W_out,
    const float* __restrict__ b_off, const float* __restrict__ b_attn,
    unsigned short* __restrict__ Wst, unsigned short* __restrict__ Wct,
    unsigned short* __restrict__ Wot, float* __restrict__ cbias)
{
    int idx = blockIdx.x * 256 + threadIdx.x;
    if (idx < 65536) {
        int n = idx >> 8, k = idx & 255;
        Wst[(((n >> 7) * 32 + (k >> 3)) * 128 + (n & 127)) * 8 + (k & 7)] =
            f2h_u(W_val[k * 256 + n]);
    } else if (idx < 65536 + 73728) {
        int j = idx - 65536;
        int n = j >> 8, k = j & 255;
        Wct[j] = f2h_u(n < 192 ? W_off[k * 192 + n] : W_attn[k * 96 + (n - 192)]);
    } else if (idx < 204800) {
        int j = idx - 139264;
        int n = j >> 8, k = j & 255;
        Wot[j] = f2h_u(W_out[k * 256 + n]);
    } else if (idx < 205088) {
        int j = idx - 204800;
        cbias[j] = (j < 192) ? b_off[j] : b_attn[j - 192];
    }
}

// ---------------- value GEMM: val = f16(enc @ W_val + b_val) ----------------
// One block = 64 rows x all 256 cols. B kept whole-half in LDS (64KB),
// staged once per half via global_load_lds (16B). A streams global->VGPR
// directly (no LDS, no per-kt barrier). Epilogue aliases the B LDS region.
__global__ __launch_bounds__(256, 2) void gemm_value(
    const float* __restrict__ A, const unsigned short* __restrict__ Wst,
    const float* __restrict__ bias, unsigned short* __restrict__ out)
{
    __shared__ __align__(16) unsigned short Bs[32 * 128 * 8];   // 64 KB
    const int tid  = threadIdx.x;
    const int wave = tid >> 6;
    const int lane = tid & 63;
    const int l15  = lane & 15;
    const int qd   = lane >> 4;
    const size_t m0 = (size_t)blockIdx.x * 64;

    // ---- issue B half0 staging: 64 x 1KB chunks, 16 per wave ----
#pragma unroll
    for (int it = 0; it < 16; ++it) {
        const int c = wave * 16 + it;
        const unsigned short* gp = Wst + c * 512 + lane * 8;
        unsigned short* lp = Bs + c * 512;      // wave-uniform base
        __builtin_amdgcn_global_load_lds(
            (const __attribute__((address_space(1))) void*)gp,
            (__attribute__((address_space(3))) void*)lp, 16, 0, 0);
    }

    // ---- A fragment loads straight to registers (16 dwordx4 in flight) ----
    const float* arow = A + (m0 + wave * 16 + l15) * 256 + qd * 8;
    float4 a0[8], a1[8];
#pragma unroll
    for (int kt = 0; kt < 8; ++kt) {
        a0[kt] = *(const float4*)(arow + kt * 32);
        a1[kt] = *(const float4*)(arow + kt * 32 + 4);
    }
    f16x8 af[8];
#pragma unroll
    for (int kt = 0; kt < 8; ++kt) {
        union { f16x8 v; uint4 u; } t;
        t.u.x = pk2(a0[kt].x, a0[kt].y);
        t.u.y = pk2(a0[kt].z, a0[kt].w);
        t.u.z = pk2(a1[kt].x, a1[kt].y);
        t.u.w = pk2(a1[kt].z, a1[kt].w);
        af[kt] = t.v;
    }

    f32x4 acc[2][8];
#pragma unroll
    for (int h = 0; h < 2; ++h)
#pragma unroll
        for (int i = 0; i < 8; ++i) acc[h][i] = (f32x4){0.f, 0.f, 0.f, 0.f};

    __syncthreads();    // half0 staged (barrier drains vmcnt)

    // ---- MFMA half0: b-frag = Bs[kgrp][n][8], conflict-free b128 ----
#pragma unroll
    for (int kt = 0; kt < 8; ++kt) {
#pragma unroll
        for (int ni = 0; ni < 8; ++ni) {
            f16x8 bf = *(const f16x8*)&Bs[(((kt * 4 + qd) * 128) + ni * 16 + l15) * 8];
            acc[0][ni] = __builtin_amdgcn_mfma_f32_16x16x32_f16(af[kt], bf, acc[0][ni], 0, 0, 0);
        }
    }
    __syncthreads();    // all waves done reading half0

    // ---- stage + compute half1 ----
#pragma unroll
    for (int it = 0; it < 16; ++it) {
        const int c = wave * 16 + it;
        const unsigned short* gp = Wst + 32768 + c * 512 + lane * 8;
        unsigned short* lp = Bs + c * 512;
        __builtin_amdgcn_global_load_lds(
            (const __attribute__((address_space(1))) void*)gp,
            (__attribute__((address_space(3))) void*)lp, 16, 0, 0);
    }
    __syncthreads();
#pragma unroll
    for (int kt = 0; kt < 8; ++kt) {
#pragma unroll
        for (int ni = 0; ni < 8; ++ni) {
            f16x8 bf = *(const f16x8*)&Bs[(((kt * 4 + qd) * 128) + ni * 16 + l15) * 8];
            acc[1][ni] = __builtin_amdgcn_mfma_f32_16x16x32_f16(af[kt], bf, acc[1][ni], 0, 0, 0);
        }
    }

    // ---- epilogue: per half, stage f16 tile in LDS (alias Bs), write coalesced ----
    constexpr int LDH = 136;     // ushorts; 272B row pitch (16B-aligned)
#pragma unroll
    for (int h = 0; h < 2; ++h) {
        __syncthreads();     // previous LDS use complete
        unsigned short* Ch = Bs;
#pragma unroll
        for (int ni = 0; ni < 8; ++ni) {
            const float bb = bias[h * 128 + ni * 16 + l15];
#pragma unroll
            for (int r = 0; r < 4; ++r) {
                Ch[(wave * 16 + qd * 4 + r) * LDH + ni * 16 + l15] =
                    f2h_u(acc[h][ni][r] + bb);
            }
        }
        __syncthreads();
        for (int f = tid; f < 64 * 16; f += 256) {
            int row = f >> 4, c8 = f & 15;
            uint4 v = *(uint4*)&Ch[row * LDH + c8 * 8];
            *(uint4*)(out + (m0 + row) * 256 + h * 128 + c8 * 8) = v;
        }
    }
}

// ---------------- small MFMA GEMM (round-1 body): C = A(f32,Mx256)*Wt^T + bias ----------------
template<int BN>
__global__ __launch_bounds__(256) void gemm_f16(
    const float* __restrict__ A, const unsigned short* __restrict__ Wt,
    const float* __restrict__ bias, float* __restrict__ outp, int ldo)
{
    constexpr int NI  = BN / 16;
    constexpr int LDA = 40;
    constexpr int LDB = 40;
    constexpr int LDC = BN + 4;
    constexpr int SM1 = 64 * LDA * 2 + BN * LDB * 2;
    constexpr int SM2 = 64 * LDC * 4;
    constexpr int SMEM = SM1 > SM2 ? SM1 : SM2;
    __shared__ __align__(16) char smem[SMEM];
    unsigned short* As = (unsigned short*)smem;
    unsigned short* Bs = (unsigned short*)(smem + 64 * LDA * 2);
    float* Cs = (float*)smem;

    const int tid  = threadIdx.x;
    const int wave = tid >> 6;
    const int lane = tid & 63;
    const int l15  = lane & 15;
    const int qd   = lane >> 4;
    const int m0   = blockIdx.y * 64;
    const int n0   = blockIdx.x * BN;

    f32x4 acc[NI];
#pragma unroll
    for (int i = 0; i < NI; i++) acc[i] = (f32x4){0.f, 0.f, 0.f, 0.f};

#pragma unroll
    for (int kt = 0; kt < 8; kt++) {
#pragma unroll
        for (int i = 0; i < 2; i++) {
            int f = tid + i * 256;
            int row = f >> 3, c4 = f & 7;
            const float4 v = *(const float4*)(A + (size_t)(m0 + row) * 256 + kt * 32 + c4 * 4);
            uint2 p;
            p.x = pk2(v.x, v.y);
            p.y = pk2(v.z, v.w);
            *(uint2*)&As[row * LDA + c4 * 4] = p;
        }
        for (int f = tid; f < BN * 4; f += 256) {
            int row = f >> 2, ch = f & 3;
            uint4 v = *(const uint4*)(Wt + (size_t)(n0 + row) * 256 + kt * 32 + ch * 8);
            *(uint4*)&Bs[row * LDB + ch * 8] = v;
        }
        __syncthreads();
        f16x8 afr = *(const f16x8*)&As[(wave * 16 + l15) * LDA + qd * 8];
#pragma unroll
        for (int ni = 0; ni < NI; ni++) {
            f16x8 fb = *(const f16x8*)&Bs[(ni * 16 + l15) * LDB + qd * 8];
            acc[ni] = __builtin_amdgcn_mfma_f32_16x16x32_f16(afr, fb, acc[ni], 0, 0, 0);
        }
        __syncthreads();
    }

#pragma unroll
    for (int ni = 0; ni < NI; ni++) {
#pragma unroll
        for (int r = 0; r < 4; r++) {
            Cs[(wave * 16 + qd * 4 + r) * LDC + ni * 16 + l15] = acc[ni][r];
        }
    }
    __syncthreads();
    for (int f = tid; f < 64 * (BN / 4); f += 256) {
        int row = f / (BN / 4), c4 = f % (BN / 4);
        float4 v = *(const float4*)&Cs[row * LDC + c4 * 4];
        const float4 bb = *(const float4*)(bias + n0 + c4 * 4);
        v.x += bb.x; v.y += bb.y; v.z += bb.z; v.w += bb.w;
        *(float4*)(outp + (size_t)(m0 + row) * ldo + n0 + c4 * 4) = v;
    }
}

// ---------------- fused softmax + loc + bilinear sampling + attn weighting ----------------
// 2 query-rows per block; 128 threads per row = (h, channel-pair); uint (2xf16) taps.
__global__ __launch_bounds__(256) void sample_attn(
    const float* __restrict__ P, const float* __restrict__ refp,
    const unsigned short* __restrict__ val, float* __restrict__ out_attn)
{
    __shared__ float sLoc[2][8][12][3];
    const int tid = threadIdx.x;
    const int rr  = tid >> 7;
    const int t   = tid & 127;
    const int row = blockIdx.x * 2 + rr;     // b*300 + q
    const int b   = row / 300;

    const float4 r4 = *(const float4*)(refp + (size_t)row * 4);

    if (t < 96) {
        const int h = t / 12, p = t - h * 12;
        const float* Pr = P + (size_t)row * 288;
        const float offx  = Pr[h * 24 + p * 2];
        const float offy  = Pr[h * 24 + p * 2 + 1];
        float m = -1e30f;
#pragma unroll
        for (int j = 0; j < 12; j++) m = fmaxf(m, Pr[192 + h * 12 + j]);
        float s = 0.f;
#pragma unroll
        for (int j = 0; j < 12; j++) s += expf(Pr[192 + h * 12 + j] - m);
        const float w = expf(Pr[192 + h * 12 + p] - m) / s;
        sLoc[rr][h][p][0] = r4.x + offx * 0.125f * r4.z;
        sLoc[rr][h][p][1] = r4.y + offy * 0.125f * r4.w;
        sLoc[rr][h][p][2] = w;
    }
    __syncthreads();

    const int hh = t >> 4;          // head
    const int cp = t & 15;          // channel pair
    const unsigned short* vb = val + (size_t)b * 8400 * 256 + hh * 32 + cp * 2;
    float acc0 = 0.f, acc1 = 0.f;
#pragma unroll
    for (int p2 = 0; p2 < 12; p2++) {
        const int lvl  = p2 >> 2;
        const int W    = (lvl == 0) ? 80 : ((lvl == 1) ? 40 : 20);
        const int loff = (lvl == 0) ? 0 : ((lvl == 1) ? 6400 : 8000);
        const float lx = sLoc[rr][hh][p2][0];
        const float ly = sLoc[rr][hh][p2][1];
        const float w  = sLoc[rr][hh][p2][2];
        const float px = lx * (float)W - 0.5f;
        const float py = ly * (float)W - 0.5f;
        const float x0f = floorf(px), y0f = floorf(py);
        const float fx = px - x0f, fy = py - y0f;
        const int x0 = (int)x0f, y0 = (int)y0f;
        const int x1 = x0 + 1, y1 = y0 + 1;
        const float w00 = (1.f - fx) * (1.f - fy);
        const float w10 = fx * (1.f - fy);
        const float w01 = (1.f - fx) * fy;
        const float w11 = fx * fy;
        const bool vx0 = (x0 >= 0) && (x0 < W);
        const bool vx1 = (x1 >= 0) && (x1 < W);
        const bool vy0 = (y0 >= 0) && (y0 < W);
        const bool vy1 = (y1 >= 0) && (y1 < W);
        const int x0c = min(max(x0, 0), W - 1), x1c = min(max(x1, 0), W - 1);
        const int y0c = min(max(y0, 0), W - 1), y1c = min(max(y1, 0), W - 1);
        const unsigned u00 = *(const unsigned*)(vb + (size_t)(loff + y0c * W + x0c) * 256);
        const unsigned u10 = *(const unsigned*)(vb + (size_t)(loff + y0c * W + x1c) * 256);
        const unsigned u01 = *(const unsigned*)(vb + (size_t)(loff + y1c * W + x0c) * 256);
        const unsigned u11 = *(const unsigned*)(vb + (size_t)(loff + y1c * W + x1c) * 256);
        const float k00 = (vx0 && vy0) ? w00 : 0.f;
        const float k10 = (vx1 && vy0) ? w10 : 0.f;
        const float k01 = (vx0 && vy1) ? w01 : 0.f;
        const float k11 = (vx1 && vy1) ? w11 : 0.f;
        acc0 += w * (k00 * h2f_u(u00 & 0xffff) + k10 * h2f_u(u10 & 0xffff)
                   + k01 * h2f_u(u01 & 0xffff) + k11 * h2f_u(u11 & 0xffff));
        acc1 += w * (k00 * h2f_u(u00 >> 16) + k10 * h2f_u(u10 >> 16)
                   + k01 * h2f_u(u01 >> 16) + k11 * h2f_u(u11 >> 16));
    }
    float2 o; o.x = acc0; o.y = acc1;
    *(float2*)(out_attn + (size_t)row * 256 + hh * 32 + cp * 2) = o;
}

extern "C" void kernel_launch(void* const* d_in, const int* in_sizes, int n_in,
                              void* d_out, int out_size, void* d_ws, size_t ws_size,
                              hipStream_t stream)
{
    const float* hs     = (const float*)d_in[0];
    const float* enc    = (const float*)d_in[1];
    const float* refp   = (const float*)d_in[2];
    const float* W_off  = (const float*)d_in[3];
    const float* b_off  = (const float*)d_in[4];
    const float* W_attn = (const float*)d_in[5];
    const float* b_attn = (const float*)d_in[6];
    const float* W_val  = (const float*)d_in[7];
    const float* b_val  = (const float*)d_in[8];
    const float* W_out  = (const float*)d_in[9];
    const float* b_out  = (const float*)d_in[10];
    float* outp = (float*)d_out;

    // workspace layout (bytes)
    char* ws = (char*)d_ws;
    unsigned short* val = (unsigned short*)ws;                 // 268800*256*2 = 137,625,600
    float* P            = (float*)(ws + 137625600);            // 9600*288*4   =  11,059,200
    float* oattn        = (float*)(ws + 148684800);            // 9600*256*4   =   9,830,400
    unsigned short* Wst = (unsigned short*)(ws + 158515200);   // 256*256*2
    unsigned short* Wct = (unsigned short*)(ws + 158646272);   // 288*256*2
    unsigned short* Wot = (unsigned short*)(ws + 158793728);   // 256*256*2
    float* cbias        = (float*)(ws + 158924800);            // 288*4

    prep_weights<<<802, 256, 0, stream>>>(W_val, W_off, W_attn, W_out,
                                          b_off, b_attn, Wst, Wct, Wot, cbias);
    // proj: (9600x256) @ (256x288) -> P (f32)
    gemm_f16<96><<<dim3(3, 150), 256, 0, stream>>>(hs, Wct, cbias, P, 288);
    // value: (268800x256) @ (256x256) -> val (f16), B-resident streaming kernel
    gemm_value<<<4200, 256, 0, stream>>>(enc, Wst, b_val, val);
    // fused sampling (2 rows per block)
    sample_attn<<<4800, 256, 0, stream>>>(P, refp, val, oattn);
    // out: (9600x256) @ (256x256) -> d_out (f32)
    gemm_f16<64><<<dim3(4, 150), 256, 0, stream>>>(oattn, Wot, b_out, outp, 256);
}

// Round 4
// 476.568 us; speedup vs baseline: 1.3186x; 1.0018x over previous
//
#include <hip/hip_runtime.h>
#include <hip/hip_fp16.h>

#define DEVI __device__ __forceinline__

typedef _Float16 f16x8 __attribute__((ext_vector_type(8)));
typedef float f32x4 __attribute__((ext_vector_type(4)));

static DEVI unsigned short f2h_u(float f) {
    _Float16 h = (_Float16)f;
    return __builtin_bit_cast(unsigned short, h);
}
static DEVI float h2f_u(unsigned short u) {
    return (float)__builtin_bit_cast(_Float16, u);
}
static DEVI unsigned pk2(float a, float b) {
    return (unsigned)f2h_u(a) | ((unsigned)f2h_u(b) << 16);
}

// problem constants
// B=32 Q=300 D=256 H=8 C=32 S=8400 levels (80,80)(40,40)(20,20) P=12

// ---------------- kernel 0: weight prep ----------------
__global__ __launch_bounds__(256) void prep_weights(
    const float* __restrict__ W_val, const float* __restrict__ W_off,
    const float* __restrict__ W_attn, const float* __restrict__ W_out,
    const float* __restrict__ b_off, const float* __restrict__ b_attn,
    unsigned short* __restrict__ Wst, unsigned short* __restrict__ Wct,
    unsigned short* __restrict__ Wot, float* __restrict__ cbias)
{
    int idx = blockIdx.x * 256 + threadIdx.x;
    if (idx < 65536) {
        int n = idx >> 8, k = idx & 255;
        Wst[(((n >> 7) * 32 + (k >> 3)) * 128 + (n & 127)) * 8 + (k & 7)] =
            f2h_u(W_val[k * 256 + n]);
    } else if (idx < 65536 + 73728) {
        int j = idx - 65536;
        int n = j >> 8, k = j & 255;
        Wct[j] = f2h_u(n < 192 ? W_off[k * 192 + n] : W_attn[k * 96 + (n - 192)]);
    } else if (idx < 204800) {
        int j = idx - 139264;
        int n = j >> 8, k = j & 255;
        Wot[j] = f2h_u(W_out[k * 256 + n]);
    } else if (idx < 205088) {
        int j = idx - 204800;
        cbias[j] = (j < 192) ? b_off[j] : b_attn[j - 192];
    }
}

// ---------------- value GEMM: val = f16(enc @ W_val + b_val) ----------------
__global__ __launch_bounds__(256, 2) void gemm_value(
    const float* __restrict__ A, const unsigned short* __restrict__ Wst,
    const float* __restrict__ bias, unsigned short* __restrict__ out)
{
    __shared__ __align__(16) unsigned short Bs[32 * 128 * 8];   // 64 KB
    const int tid  = threadIdx.x;
    const int wave = tid >> 6;
    const int lane = tid & 63;
    const int l15  = lane & 15;
    const int qd   = lane >> 4;
    const size_t m0 = (size_t)blockIdx.x * 64;

#pragma unroll
    for (int it = 0; it < 16; ++it) {
        const int c = wave * 16 + it;
        const unsigned short* gp = Wst + c * 512 + lane * 8;
        unsigned short* lp = Bs + c * 512;
        __builtin_amdgcn_global_load_lds(
            (const __attribute__((address_space(1))) void*)gp,
            (__attribute__((address_space(3))) void*)lp, 16, 0, 0);
    }

    const float* arow = A + (m0 + wave * 16 + l15) * 256 + qd * 8;
    float4 a0[8], a1[8];
#pragma unroll
    for (int kt = 0; kt < 8; ++kt) {
        a0[kt] = *(const float4*)(arow + kt * 32);
        a1[kt] = *(const float4*)(arow + kt * 32 + 4);
    }
    f16x8 af[8];
#pragma unroll
    for (int kt = 0; kt < 8; ++kt) {
        union { f16x8 v; uint4 u; } t;
        t.u.x = pk2(a0[kt].x, a0[kt].y);
        t.u.y = pk2(a0[kt].z, a0[kt].w);
        t.u.z = pk2(a1[kt].x, a1[kt].y);
        t.u.w = pk2(a1[kt].z, a1[kt].w);
        af[kt] = t.v;
    }

    f32x4 acc[2][8];
#pragma unroll
    for (int h = 0; h < 2; ++h)
#pragma unroll
        for (int i = 0; i < 8; ++i) acc[h][i] = (f32x4){0.f, 0.f, 0.f, 0.f};

    __syncthreads();

#pragma unroll
    for (int kt = 0; kt < 8; ++kt) {
#pragma unroll
        for (int ni = 0; ni < 8; ++ni) {
            f16x8 bf = *(const f16x8*)&Bs[(((kt * 4 + qd) * 128) + ni * 16 + l15) * 8];
            acc[0][ni] = __builtin_amdgcn_mfma_f32_16x16x32_f16(af[kt], bf, acc[0][ni], 0, 0, 0);
        }
    }
    __syncthreads();

#pragma unroll
    for (int it = 0; it < 16; ++it) {
        const int c = wave * 16 + it;
        const unsigned short* gp = Wst + 32768 + c * 512 + lane * 8;
        unsigned short* lp = Bs + c * 512;
        __builtin_amdgcn_global_load_lds(
            (const __attribute__((address_space(1))) void*)gp,
            (__attribute__((address_space(3))) void*)lp, 16, 0, 0);
    }
    __syncthreads();
#pragma unroll
    for (int kt = 0; kt < 8; ++kt) {
#pragma unroll
        for (int ni = 0; ni < 8; ++ni) {
            f16x8 bf = *(const f16x8*)&Bs[(((kt * 4 + qd) * 128) + ni * 16 + l15) * 8];
            acc[1][ni] = __builtin_amdgcn_mfma_f32_16x16x32_f16(af[kt], bf, acc[1][ni], 0, 0, 0);
        }
    }

    constexpr int LDH = 136;
#pragma unroll
    for (int h = 0; h < 2; ++h) {
        __syncthreads();
        unsigned short* Ch = Bs;
#pragma unroll
        for (int ni = 0; ni < 8; ++ni) {
            const float bb = bias[h * 128 + ni * 16 + l15];
#pragma unroll
            for (int r = 0; r < 4; ++r) {
                Ch[(wave * 16 + qd * 4 + r) * LDH + ni * 16 + l15] =
                    f2h_u(acc[h][ni][r] + bb);
            }
        }
        __syncthreads();
        for (int f = tid; f < 64 * 16; f += 256) {
            int row = f >> 4, c8 = f & 15;
            uint4 v = *(uint4*)&Ch[row * LDH + c8 * 8];
            *(uint4*)(out + (m0 + row) * 256 + h * 128 + c8 * 8) = v;
        }
    }
}

// ---------------- small MFMA GEMM: C = A(f32,Mx256)*Wt^T + bias ----------------
template<int BN>
__global__ __launch_bounds__(256) void gemm_f16(
    const float* __restrict__ A, const unsigned short* __restrict__ Wt,
    const float* __restrict__ bias, float* __restrict__ outp, int ldo)
{
    constexpr int NI  = BN / 16;
    constexpr int LDA = 40;
    constexpr int LDB = 40;
    constexpr int LDC = BN + 4;
    constexpr int SM1 = 64 * LDA * 2 + BN * LDB * 2;
    constexpr int SM2 = 64 * LDC * 4;
    constexpr int SMEM = SM1 > SM2 ? SM1 : SM2;
    __shared__ __align__(16) char smem[SMEM];
    unsigned short* As = (unsigned short*)smem;
    unsigned short* Bs = (unsigned short*)(smem + 64 * LDA * 2);
    float* Cs = (float*)smem;

    const int tid  = threadIdx.x;
    const int wave = tid >> 6;
    const int lane = tid & 63;
    const int l15  = lane & 15;
    const int qd   = lane >> 4;
    const int m0   = blockIdx.y * 64;
    const int n0   = blockIdx.x * BN;

    f32x4 acc[NI];
#pragma unroll
    for (int i = 0; i < NI; i++) acc[i] = (f32x4){0.f, 0.f, 0.f, 0.f};

#pragma unroll
    for (int kt = 0; kt < 8; kt++) {
#pragma unroll
        for (int i = 0; i < 2; i++) {
            int f = tid + i * 256;
            int row = f >> 3, c4 = f & 7;
            const float4 v = *(const float4*)(A + (size_t)(m0 + row) * 256 + kt * 32 + c4 * 4);
            uint2 p;
            p.x = pk2(v.x, v.y);
            p.y = pk2(v.z, v.w);
            *(uint2*)&As[row * LDA + c4 * 4] = p;
        }
        for (int f = tid; f < BN * 4; f += 256) {
            int row = f >> 2, ch = f & 3;
            uint4 v = *(const uint4*)(Wt + (size_t)(n0 + row) * 256 + kt * 32 + ch * 8);
            *(uint4*)&Bs[row * LDB + ch * 8] = v;
        }
        __syncthreads();
        f16x8 afr = *(const f16x8*)&As[(wave * 16 + l15) * LDA + qd * 8];
#pragma unroll
        for (int ni = 0; ni < NI; ni++) {
            f16x8 fb = *(const f16x8*)&Bs[(ni * 16 + l15) * LDB + qd * 8];
            acc[ni] = __builtin_amdgcn_mfma_f32_16x16x32_f16(afr, fb, acc[ni], 0, 0, 0);
        }
        __syncthreads();
    }

#pragma unroll
    for (int ni = 0; ni < NI; ni++) {
#pragma unroll
        for (int r = 0; r < 4; r++) {
            Cs[(wave * 16 + qd * 4 + r) * LDC + ni * 16 + l15] = acc[ni][r];
        }
    }
    __syncthreads();
    for (int f = tid; f < 64 * (BN / 4); f += 256) {
        int row = f / (BN / 4), c4 = f % (BN / 4);
        float4 v = *(const float4*)&Cs[row * LDC + c4 * 4];
        const float4 bb = *(const float4*)(bias + n0 + c4 * 4);
        v.x += bb.x; v.y += bb.y; v.z += bb.z; v.w += bb.w;
        *(float4*)(outp + (size_t)(m0 + row) * ldo + n0 + c4 * 4) = v;
    }
}

// ---------------- fused softmax + loc + bilinear sampling + attn weighting ----------------
// Block = 4 consecutive query-rows of ONE batch b. XCD-affinity swizzle:
// xcd = blk%8 handles b ≡ xcd (mod 8) -> each XCD's L2 holds ~one 4.3MB b-slice.
// Thread = (row r=tid>>6, head h, lane8): 4 channels via uint2 (8B) loads.
// Per 6-point half: compute 24 tap offsets+weights, THEN batch-issue 24 loads.
__global__ __launch_bounds__(256) void sample_attn(
    const float* __restrict__ P, const float* __restrict__ refp,
    const unsigned short* __restrict__ val, float* __restrict__ out_attn)
{
    __shared__ float sP[1152];             // 4 rows x 288
    __shared__ float sLoc[4][8][12][3];
    const int tid   = threadIdx.x;
    const int blk   = blockIdx.x;
    const int xcd   = blk & 7;
    const int local = blk >> 3;            // [0,300)
    const int b     = xcd + 8 * (local / 75);
    const int q0    = (local % 75) * 4;
    const int row0  = b * 300 + q0;

    // phase 0: stage 4 P-rows (contiguous) into LDS
    {
        const float4* src = (const float4*)(P + (size_t)row0 * 288);
        for (int f = tid; f < 288; f += 256) ((float4*)sP)[f] = src[f];
    }
    __syncthreads();

    // phase 1: 384 (r,h,p) jobs -> softmax weight + location
    for (int j = tid; j < 384; j += 256) {
        const int r = j / 96, rem = j - r * 96;
        const int h = rem / 12, p = rem - h * 12;
        const float* Pr = sP + r * 288;
        const float* Lg = Pr + 192 + h * 12;
        float m = -1e30f;
#pragma unroll
        for (int jj = 0; jj < 12; jj++) m = fmaxf(m, Lg[jj]);
        float s = 0.f;
#pragma unroll
        for (int jj = 0; jj < 12; jj++) s += __expf(Lg[jj] - m);
        const float w = __expf(Lg[p] - m) / s;
        const float4 r4 = *(const float4*)(refp + (size_t)(row0 + r) * 4);
        sLoc[r][h][p][0] = r4.x + Pr[h * 24 + p * 2]     * 0.125f * r4.z;
        sLoc[r][h][p][1] = r4.y + Pr[h * 24 + p * 2 + 1] * 0.125f * r4.w;
        sLoc[r][h][p][2] = w;
    }
    __syncthreads();

    // phase 2: gather + weight. thread=(r,h,l8), 4 channels.
    const int r  = tid >> 6;
    const int t6 = tid & 63;
    const int h  = t6 >> 3;
    const int l8 = t6 & 7;
    const int row = row0 + r;
    const unsigned short* vb = val + (size_t)b * 8400 * 256 + h * 32 + l8 * 4;

    float a0 = 0.f, a1 = 0.f, a2 = 0.f, a3 = 0.f;
#pragma unroll
    for (int half = 0; half < 2; ++half) {
        int   off[24];
        float kw[24];
#pragma unroll
        for (int pp = 0; pp < 6; ++pp) {
            const int p2   = half * 6 + pp;
            const int lvl  = p2 >> 2;
            const int W    = (lvl == 0) ? 80 : ((lvl == 1) ? 40 : 20);
            const int loff = (lvl == 0) ? 0 : ((lvl == 1) ? 6400 : 8000);
            const float lx = sLoc[r][h][p2][0];
            const float ly = sLoc[r][h][p2][1];
            const float w  = sLoc[r][h][p2][2];
            const float px = lx * (float)W - 0.5f;
            const float py = ly * (float)W - 0.5f;
            const float x0f = floorf(px), y0f = floorf(py);
            const float fx = px - x0f, fy = py - y0f;
            const int x0 = (int)x0f, y0 = (int)y0f;
            const int x1 = x0 + 1, y1 = y0 + 1;
            const bool vx0 = (x0 >= 0) && (x0 < W);
            const bool vx1 = (x1 >= 0) && (x1 < W);
            const bool vy0 = (y0 >= 0) && (y0 < W);
            const bool vy1 = (y1 >= 0) && (y1 < W);
            const int x0c = min(max(x0, 0), W - 1), x1c = min(max(x1, 0), W - 1);
            const int y0c = min(max(y0, 0), W - 1), y1c = min(max(y1, 0), W - 1);
            kw[pp * 4 + 0] = (vx0 && vy0) ? w * (1.f - fx) * (1.f - fy) : 0.f;
            kw[pp * 4 + 1] = (vx1 && vy0) ? w * fx * (1.f - fy) : 0.f;
            kw[pp * 4 + 2] = (vx0 && vy1) ? w * (1.f - fx) * fy : 0.f;
            kw[pp * 4 + 3] = (vx1 && vy1) ? w * fx * fy : 0.f;
            off[pp * 4 + 0] = (loff + y0c * W + x0c) * 256;
            off[pp * 4 + 1] = (loff + y0c * W + x1c) * 256;
            off[pp * 4 + 2] = (loff + y1c * W + x0c) * 256;
            off[pp * 4 + 3] = (loff + y1c * W + x1c) * 256;
        }
        uint2 u[24];
#pragma unroll
        for (int t = 0; t < 24; ++t) u[t] = *(const uint2*)(vb + off[t]);
#pragma unroll
        for (int t = 0; t < 24; ++t) {
            const float k = kw[t];
            a0 = fmaf(k, h2f_u(u[t].x & 0xffff), a0);
            a1 = fmaf(k, h2f_u(u[t].x >> 16),    a1);
            a2 = fmaf(k, h2f_u(u[t].y & 0xffff), a2);
            a3 = fmaf(k, h2f_u(u[t].y >> 16),    a3);
        }
    }
    float4 o; o.x = a0; o.y = a1; o.z = a2; o.w = a3;
    *(float4*)(out_attn + (size_t)row * 256 + h * 32 + l8 * 4) = o;
}

extern "C" void kernel_launch(void* const* d_in, const int* in_sizes, int n_in,
                              void* d_out, int out_size, void* d_ws, size_t ws_size,
                              hipStream_t stream)
{
    const float* hs     = (const float*)d_in[0];
    const float* enc    = (const float*)d_in[1];
    const float* refp   = (const float*)d_in[2];
    const float* W_off  = (const float*)d_in[3];
    const float* b_off  = (const float*)d_in[4];
    const float* W_attn = (const float*)d_in[5];
    const float* b_attn = (const float*)d_in[6];
    const float* W_val  = (const float*)d_in[7];
    const float* b_val  = (const float*)d_in[8];
    const float* W_out  = (const float*)d_in[9];
    const float* b_out  = (const float*)d_in[10];
    float* outp = (float*)d_out;

    // workspace layout (bytes)
    char* ws = (char*)d_ws;
    unsigned short* val = (unsigned short*)ws;                 // 137,625,600
    float* P            = (float*)(ws + 137625600);            // 11,059,200
    float* oattn        = (float*)(ws + 148684800);            //  9,830,400
    unsigned short* Wst = (unsigned short*)(ws + 158515200);
    unsigned short* Wct = (unsigned short*)(ws + 158646272);
    unsigned short* Wot = (unsigned short*)(ws + 158793728);
    float* cbias        = (float*)(ws + 158924800);

    prep_weights<<<802, 256, 0, stream>>>(W_val, W_off, W_attn, W_out,
                                          b_off, b_attn, Wst, Wct, Wot, cbias);
    gemm_f16<96><<<dim3(3, 150), 256, 0, stream>>>(hs, Wct, cbias, P, 288);
    gemm_value<<<4200, 256, 0, stream>>>(enc, Wst, b_val, val);
    sample_attn<<<2400, 256, 0, stream>>>(P, refp, val, oattn);
    gemm_f16<64><<<dim3(4, 150), 256, 0, stream>>>(oattn, Wot, b_out, outp, 256);
}